// Round 1
// 383.460 us; speedup vs baseline: 1.0036x; 1.0036x over previous
//
#include <hip/hip_runtime.h>
#include <math.h>

// PlanarFlow: B=16384 rows, 32 steps, latent 64.
// RESTRUCTURED: one wave = 4 rows; 16 lanes per row; lane owns z[4i..4i+3]
// as float4. All global traffic is dwordx4 (16 B/lane). Per-row reductions
// are 16-lane row_ror DPP cascades (4 ops, result in ALL lanes -> no
// readlane/broadcast step). Per-step b[s] from a bank-conflict-free LDS
// table. Bytes moved unchanged (~287 MB); VMEM instr count /4; per-row
// VALU issue /~3.5.

constexpr int BATCH = 16384;
constexpr int STEPS = 32;
constexpr int LAT   = 64;
constexpr int IN_W  = STEPS * (2 * LAT + 1) + 2 * LAT;  // 4256

template <int CTRL>
__device__ __forceinline__ float dpp_mov(float x) {
    // bound_ctrl=true: invalid source lanes read 0 (identity for add)
    return __int_as_float(
        __builtin_amdgcn_update_dpp(0, __float_as_int(x), CTRL, 0xF, 0xF, true));
}

// Sum across each 16-lane DPP row; EVERY lane of the row gets the full sum.
// row_ror has no invalid lanes, so the rotate-add cascade is exact.
__device__ __forceinline__ float rowsum16(float x) {
    x += dpp_mov<0x121>(x);  // row_ror:1
    x += dpp_mov<0x122>(x);  // row_ror:2
    x += dpp_mov<0x124>(x);  // row_ror:4
    x += dpp_mov<0x128>(x);  // row_ror:8
    return x;
}

// Full-wave sum to lane 63 (other lanes hold partials).
__device__ __forceinline__ float wave_reduce_to63(float x) {
    x += dpp_mov<0x111>(x);  // row_shr:1
    x += dpp_mov<0x112>(x);  // row_shr:2
    x += dpp_mov<0x114>(x);  // row_shr:4
    x += dpp_mov<0x118>(x);  // row_shr:8
    x += dpp_mov<0x142>(x);  // row_bcast:15
    x += dpp_mov<0x143>(x);  // row_bcast:31
    return x;
}

__global__ __launch_bounds__(256)
void planar_flow_kernel(const float* __restrict__ inputs,
                        const float* __restrict__ noise,
                        float* __restrict__ z_out,
                        float* __restrict__ loss_out)
{
    const int lane = threadIdx.x & 63;
    const int wv   = threadIdx.x >> 6;   // wave within block (0..3)
    const int g    = lane >> 4;          // row-group within wave (0..3)
    const int i    = lane & 15;          // quad index within row (0..15)

    const int row = (((blockIdx.x << 2) + wv) << 2) + g;   // 4 rows per wave

    const float* rp = inputs + (size_t)row * IN_W;

    // b table: sb[wv*128 + s*4 + g] = b[row(g)][s].
    // Layout [s][g]: within a wave the 4 groups read words s*4+g -> 4
    // distinct banks; the 16 lanes of a group read the same word (broadcast).
    __shared__ float sb[4 * 128];

    // ---- prologue loads (all float4, 16 B aligned; row stride 17024 B % 16 == 0) ----
    const float4 mu  = *(const float4*)(rp + 4 * i);          // [0,64)
    const float4 ls2 = *(const float4*)(rp + LAT + 4 * i);    // [64,128)
    const float4 nz  = *(const float4*)(noise + (size_t)row * LAT + 4 * i);

    const float* bp = rp + 2 * LAT + 2 * STEPS * LAT;         // [4224,4256)
    sb[wv * 128 + i * 4 + g]        = bp[i];
    sb[wv * 128 + (i + 16) * 4 + g] = bp[i + 16];
    __syncthreads();   // cheap one-time barrier; regions are wave-private anyway

    // ---- z0 and KL term ----
    float4 z;
    z.x = fmaf(nz.x, __expf(0.5f * ls2.x), mu.x);
    z.y = fmaf(nz.y, __expf(0.5f * ls2.y), mu.y);
    z.z = fmaf(nz.z, __expf(0.5f * ls2.z), mu.z);
    z.w = fmaf(nz.w, __expf(0.5f * ls2.w), mu.w);

    float klp = nz.x * nz.x + nz.y * nz.y + nz.z * nz.z + nz.w * nz.w
              + ls2.x + ls2.y + ls2.z + ls2.w;
    // identical in all 16 lanes of the group
    float acc = -0.5f * rowsum16(klp);

    const float* up  = rp + 2 * LAT;               // U: [128, 2176)
    const float* wp  = rp + 2 * LAT + STEPS * LAT; // W: [2176, 4224)
    const float* sbp = sb + wv * 128 + g;

    #pragma unroll 8
    for (int s = 0; s < STEPS; ++s) {
        const float4 u = *(const float4*)(up + s * LAT + 4 * i);
        const float4 w = *(const float4*)(wp + s * LAT + 4 * i);

        // h = w.z + b[s]  (full row dot in every lane after rowsum16)
        float hp = w.x * z.x + w.y * z.y + w.z * z.z + w.w * z.w;
        float h  = rowsum16(hp) + sbp[s * 4];

        // uw = u.w (needed only for the loss; row-uniform after rowsum16)
        float uwp = u.x * w.x + u.y * w.y + u.z * w.z + u.w * w.w;
        float uw  = rowsum16(uwp);

        // tanh(h) = 1 - 2/(exp(2h)+1); saturates correctly on overflow
        float e = __expf(2.0f * h);
        float t = 1.0f - 2.0f * __builtin_amdgcn_rcpf(e + 1.0f);

        // all 16 lanes of the group accumulate the identical row loss term
        acc -= __logf(fabsf(fmaf(1.0f - t * t, uw, 1.0f)));

        z.x = fmaf(u.x, t, z.x);
        z.y = fmaf(u.y, t, z.y);
        z.z = fmaf(u.z, t, z.z);
        z.w = fmaf(u.w, t, z.w);
    }

    // ---- write z (float4, coalesced) ----
    *(float4*)(z_out + (size_t)row * LAT + 4 * i) = z;

    // ---- loss: each row's loss is replicated across its 16 lanes, so the
    // wave sum = 16 * (sum over the wave's 4 rows). Scale by 1/16 at the end.
    __shared__ float partial[4];
    float wsum = wave_reduce_to63(acc);
    if (lane == 63) partial[wv] = wsum;
    __syncthreads();
    if (threadIdx.x == 0) {
        float s = (partial[0] + partial[1] + partial[2] + partial[3])
                * (1.0f / (16.0f * BATCH));
        atomicAdd(loss_out, s);
    }
}

extern "C" void kernel_launch(void* const* d_in, const int* in_sizes, int n_in,
                              void* d_out, int out_size, void* d_ws, size_t ws_size,
                              hipStream_t stream)
{
    const float* inputs = (const float*)d_in[0];
    const float* noise  = (const float*)d_in[1];
    float* z_out    = (float*)d_out;
    float* loss_out = (float*)d_out + (size_t)BATCH * LAT;

    // d_out is poisoned 0xAA before every timed launch — zero the loss slot.
    hipMemsetAsync(loss_out, 0, sizeof(float), stream);

    planar_flow_kernel<<<dim3(BATCH / 16), dim3(256), 0, stream>>>(
        inputs, noise, z_out, loss_out);
}